// Round 1
// baseline (635.251 us; speedup 1.0000x reference)
//
#include <hip/hip_runtime.h>

// Scaled dot-product attention, B=8 H=12 S=1024 D=64, fp32 in/out.
// Outputs (concatenated in d_out): probs (B,H,S,S) then context (B,H,S,D).
// Design: one 512-thread block per (bh, 64-row Q tile). bf16 MFMA for QK^T
// and PV; scores live in VGPRs; probs go to global in fp32 from registers
// (accuracy) and to LDS in bf16 (A-layout source for the PV MFMA).

#define SLEN 1024
#define DHEAD 64
#define NBH 96

typedef __attribute__((ext_vector_type(4))) float f32x4;
typedef __attribute__((ext_vector_type(8))) __bf16 bf16x8;

#define PL_STRIDE 1032   // 1024 + 8 bf16 pad: rows 16B-aligned, 2-way-max banks on b128 reads
#define VT_STRIDE 72     // 64 + 8 bf16 pad

struct SMem {
  __bf16 pl[64][PL_STRIDE];     // probs bf16 (A-operand source), 132096 B
  union {
    __bf16 qt[64][VT_STRIDE];   // scaled Q tile (phase 1)
    __bf16 vt[64][VT_STRIDE];   // transposed V chunk: vt[d][kk] (phase 4)
  } u;                          // 9216 B
  float red[8][64];             // per-wave softmax partials
  float mrow[64];
  float invrow[64];
};                              // total ~143.9 KB < 160 KB

__global__ __launch_bounds__(512, 2)
void attn_fused(const float* __restrict__ Qp, const float* __restrict__ Kp,
                const float* __restrict__ Vp, const int* __restrict__ scale_p,
                float* __restrict__ out) {
  __shared__ SMem sm;
  const int tid  = threadIdx.x;
  const int w    = tid >> 6;     // wave 0..7
  const int lane = tid & 63;
  const int quad = lane >> 4;
  const int c16  = lane & 15;
  const int bh   = blockIdx.y;
  const int qbase = blockIdx.x * 64;

  // scale arrives as a 1-element array; robust to int32 or fp32 encoding
  int siv = *scale_p;
  float fs = (siv >= 1 && siv <= (1 << 24)) ? (float)siv : __int_as_float(siv);
  const float inv_scale = 1.0f / fs;

  const float* Qg = Qp + ((size_t)bh * SLEN + qbase) * DHEAD;
  const float* Kg = Kp + (size_t)bh * SLEN * DHEAD;
  const float* Vg = Vp + (size_t)bh * SLEN * DHEAD;

  // ---- stage Q tile (x 1/scale) to LDS as bf16 ----
  #pragma unroll
  for (int it = 0; it < 2; ++it) {
    int flat = it * 2048 + tid * 4;
    int r = flat >> 6, d = flat & 63;
    f32x4 qv = *(const f32x4*)(Qg + (size_t)r * DHEAD + d);
    #pragma unroll
    for (int j = 0; j < 4; ++j)
      sm.u.qt[r][d + j] = (__bf16)(qv[j] * inv_scale);
  }
  __syncthreads();

  // A-frags: A[m=lane&15][k=quad*8+j]  (verified layout, m120)
  bf16x8 af[4][2];
  #pragma unroll
  for (int rt = 0; rt < 4; ++rt)
    #pragma unroll
    for (int k0 = 0; k0 < 2; ++k0)
      af[rt][k0] = *(const bf16x8*)&sm.u.qt[rt * 16 + c16][k0 * 32 + quad * 8];

  f32x4 acc[4][8];
  {
    f32x4 z = {0.0f, 0.0f, 0.0f, 0.0f};
    #pragma unroll
    for (int rt = 0; rt < 4; ++rt)
      #pragma unroll
      for (int ct = 0; ct < 8; ++ct) acc[rt][ct] = z;
  }

  // ---- phase 1: S = (Q/scale) K^T.  Wave w owns key columns [w*128, w*128+128) ----
  #pragma unroll
  for (int ct = 0; ct < 8; ++ct) {
    int krow = w * 128 + ct * 16 + c16;   // B-frag: B[k=quad*8+j][n=lane&15] = K[n][k]
    const float* kr = Kg + (size_t)krow * DHEAD + quad * 8;
    f32x4 k0a = *(const f32x4*)(kr);
    f32x4 k0b = *(const f32x4*)(kr + 4);
    f32x4 k1a = *(const f32x4*)(kr + 32);
    f32x4 k1b = *(const f32x4*)(kr + 36);
    bf16x8 b0, b1;
    #pragma unroll
    for (int j = 0; j < 4; ++j) {
      b0[j]     = (__bf16)k0a[j];
      b0[j + 4] = (__bf16)k0b[j];
      b1[j]     = (__bf16)k1a[j];
      b1[j + 4] = (__bf16)k1b[j];
    }
    #pragma unroll
    for (int rt = 0; rt < 4; ++rt) {
      acc[rt][ct] = __builtin_amdgcn_mfma_f32_16x16x32_bf16(af[rt][0], b0, acc[rt][ct], 0, 0, 0);
      acc[rt][ct] = __builtin_amdgcn_mfma_f32_16x16x32_bf16(af[rt][1], b1, acc[rt][ct], 0, 0, 0);
    }
  }

  // ---- softmax: row max (C/D layout: row = rt*16 + quad*4 + reg, col = lane&15) ----
  float mx[4][4];
  #pragma unroll
  for (int rt = 0; rt < 4; ++rt)
    #pragma unroll
    for (int i = 0; i < 4; ++i) {
      float m = acc[rt][0][i];
      #pragma unroll
      for (int ct = 1; ct < 8; ++ct) m = fmaxf(m, acc[rt][ct][i]);
      mx[rt][i] = m;
    }
  #pragma unroll
  for (int off = 1; off < 16; off <<= 1)
    #pragma unroll
    for (int rt = 0; rt < 4; ++rt)
      #pragma unroll
      for (int i = 0; i < 4; ++i)
        mx[rt][i] = fmaxf(mx[rt][i], __shfl_xor(mx[rt][i], off));
  if (c16 == 0) {
    #pragma unroll
    for (int rt = 0; rt < 4; ++rt)
      #pragma unroll
      for (int i = 0; i < 4; ++i)
        sm.red[w][rt * 16 + quad * 4 + i] = mx[rt][i];
  }
  __syncthreads();
  if (tid < 64) {
    float m = sm.red[0][tid];
    #pragma unroll
    for (int w2 = 1; w2 < 8; ++w2) m = fmaxf(m, sm.red[w2][tid]);
    sm.mrow[tid] = m;
  }
  __syncthreads();

  // ---- exp + row sum ----
  float sum4[4][4];
  #pragma unroll
  for (int rt = 0; rt < 4; ++rt)
    #pragma unroll
    for (int i = 0; i < 4; ++i) {
      float m = sm.mrow[rt * 16 + quad * 4 + i];
      float s = 0.0f;
      #pragma unroll
      for (int ct = 0; ct < 8; ++ct) {
        float e = __expf(acc[rt][ct][i] - m);
        acc[rt][ct][i] = e;
        s += e;
      }
      sum4[rt][i] = s;
    }
  #pragma unroll
  for (int off = 1; off < 16; off <<= 1)
    #pragma unroll
    for (int rt = 0; rt < 4; ++rt)
      #pragma unroll
      for (int i = 0; i < 4; ++i)
        sum4[rt][i] += __shfl_xor(sum4[rt][i], off);
  if (c16 == 0) {
    #pragma unroll
    for (int rt = 0; rt < 4; ++rt)
      #pragma unroll
      for (int i = 0; i < 4; ++i)
        sm.red[w][rt * 16 + quad * 4 + i] = sum4[rt][i];
  }
  __syncthreads();
  if (tid < 64) {
    float s = 0.0f;
    #pragma unroll
    for (int w2 = 0; w2 < 8; ++w2) s += sm.red[w2][tid];
    sm.invrow[tid] = 1.0f / s;
  }
  __syncthreads();

  // ---- phase 3: write probs (fp32 from regs -> global; bf16 -> LDS for PV) ----
  #pragma unroll
  for (int rt = 0; rt < 4; ++rt) {
    #pragma unroll
    for (int i = 0; i < 4; ++i) {
      int row = rt * 16 + quad * 4 + i;
      float inv = sm.invrow[row];
      float* orow = out + ((size_t)bh * SLEN + qbase + row) * SLEN;
      __bf16* prow = sm.pl[row];
      #pragma unroll
      for (int ct = 0; ct < 8; ++ct) {
        int col = w * 128 + ct * 16 + c16;
        float p = acc[rt][ct][i] * inv;
        orow[col] = p;
        prow[col] = (__bf16)p;
      }
    }
  }

  // ---- phase 4: context = P @ V.  Wave w -> row-tile (w&3), d-tiles {w>>2, (w>>2)+2} ----
  f32x4 ctx[2];
  {
    f32x4 z = {0.0f, 0.0f, 0.0f, 0.0f};
    ctx[0] = z; ctx[1] = z;
  }
  const int prt = w & 3;
  const int dtb = w >> 2;

  // register prefetch of V chunk 0 (64 key rows x 64 d, fp32)
  f32x4 pref[2];
  #pragma unroll
  for (int it = 0; it < 2; ++it) {
    int flat = it * 2048 + tid * 4;
    int kk = flat >> 6, d0 = flat & 63;
    pref[it] = *(const f32x4*)(Vg + (size_t)kk * DHEAD + d0);
  }

  for (int kc = 0; kc < 16; ++kc) {
    __syncthreads();  // kc==0: pl complete; else: prior vt reads complete
    #pragma unroll
    for (int it = 0; it < 2; ++it) {
      int flat = it * 2048 + tid * 4;
      int kk = flat >> 6, d0 = flat & 63;
      #pragma unroll
      for (int j = 0; j < 4; ++j)
        sm.u.vt[d0 + j][kk] = (__bf16)pref[it][j];   // transpose: vt[d][k]
    }
    if (kc < 15) {  // prefetch next chunk; latency hidden across the MFMA block below
      #pragma unroll
      for (int it = 0; it < 2; ++it) {
        int flat = it * 2048 + tid * 4;
        int kk = flat >> 6, d0 = flat & 63;
        pref[it] = *(const f32x4*)(Vg + (size_t)((kc + 1) * 64 + kk) * DHEAD + d0);
      }
    }
    __syncthreads();
    #pragma unroll
    for (int ks = 0; ks < 2; ++ks) {
      int kl = ks * 32 + quad * 8;
      bf16x8 a = *(const bf16x8*)&sm.pl[prt * 16 + c16][kc * 64 + kl];
      #pragma unroll
      for (int t2 = 0; t2 < 2; ++t2) {
        int dt = dtb + t2 * 2;
        bf16x8 b = *(const bf16x8*)&sm.u.vt[dt * 16 + c16][kl];
        ctx[t2] = __builtin_amdgcn_mfma_f32_16x16x32_bf16(a, b, ctx[t2], 0, 0, 0);
      }
    }
  }

  // ---- write context ----
  float* outC = out + (size_t)NBH * SLEN * SLEN;
  #pragma unroll
  for (int t2 = 0; t2 < 2; ++t2) {
    int dt = dtb + t2 * 2;
    #pragma unroll
    for (int i = 0; i < 4; ++i) {
      int row = prt * 16 + quad * 4 + i;
      outC[((size_t)bh * SLEN + qbase + row) * DHEAD + dt * 16 + c16] = ctx[t2][i];
    }
  }
}

extern "C" void kernel_launch(void* const* d_in, const int* in_sizes, int n_in,
                              void* d_out, int out_size, void* d_ws, size_t ws_size,
                              hipStream_t stream) {
  (void)in_sizes; (void)n_in; (void)d_ws; (void)ws_size; (void)out_size;
  const float* q = (const float*)d_in[0];
  const float* k = (const float*)d_in[1];
  const float* v = (const float*)d_in[2];
  const int* scale = (const int*)d_in[3];
  float* out = (float*)d_out;
  dim3 grid(SLEN / 64, NBH);
  dim3 block(512);
  hipLaunchKernelGGL(attn_fused, grid, block, 0, stream, q, k, v, scale, out);
}